// Round 5
// baseline (258.583 us; speedup 1.0000x reference)
//
#include <hip/hip_runtime.h>
#include <cstdint>
#include <cstddef>

#define DM 1024
#define NH 16
#define DQ 64
#define NB 8
#define LSEQ 1024

typedef __attribute__((ext_vector_type(8))) short short8;
typedef __attribute__((ext_vector_type(4))) float floatx4;

__device__ __forceinline__ unsigned short f2bf(float f) {
  union { float f; unsigned u; } v; v.f = f;
  unsigned r = v.u + 0x7FFFu + ((v.u >> 16) & 1u);
  return (unsigned short)(r >> 16);
}
__device__ __forceinline__ float bf2f(unsigned short u) {
  union { unsigned u; float f; } v; v.u = ((unsigned)u) << 16;
  return v.f;
}

__device__ __forceinline__ void async_load16(const void* g, void* l) {
  __builtin_amdgcn_global_load_lds(
      (const __attribute__((address_space(1))) unsigned int*)g,
      (__attribute__((address_space(3))) unsigned int*)l, 16, 0, 0);
}

// ---------------- prep: W transpose (z<3) + q/k f32->bf16 convert (z==3) ----------------
__global__ void prep_kernel(const float* __restrict__ q, const float* __restrict__ k,
                            const float* __restrict__ Wq, const float* __restrict__ Wk,
                            const float* __restrict__ Wv,
                            unsigned short* __restrict__ qb, unsigned short* __restrict__ kb,
                            unsigned short* __restrict__ Wt) {
  const int z = blockIdx.z;
  if (z == 3) {
    // convert q,k: 1024 blocks x 256 threads x 8 elems x 4 reps = 8.39M elems each
    const int t = threadIdx.y * 32 + threadIdx.x;
    const int bid = blockIdx.y * 32 + blockIdx.x;
#pragma unroll
    for (int rep = 0; rep < 4; rep++) {
      const size_t i = (size_t)rep * 2097152 + ((size_t)bid * 256 + t) * 8;
      float4 a0 = *(const float4*)&q[i];
      float4 a1 = *(const float4*)&q[i + 4];
      ushort4 r0, r1;
      r0.x = f2bf(a0.x); r0.y = f2bf(a0.y); r0.z = f2bf(a0.z); r0.w = f2bf(a0.w);
      r1.x = f2bf(a1.x); r1.y = f2bf(a1.y); r1.z = f2bf(a1.z); r1.w = f2bf(a1.w);
      *(ushort4*)&qb[i] = r0;
      *(ushort4*)&qb[i + 4] = r1;
      float4 b0 = *(const float4*)&k[i];
      float4 b1 = *(const float4*)&k[i + 4];
      ushort4 s0, s1;
      s0.x = f2bf(b0.x); s0.y = f2bf(b0.y); s0.z = f2bf(b0.z); s0.w = f2bf(b0.w);
      s1.x = f2bf(b1.x); s1.y = f2bf(b1.y); s1.z = f2bf(b1.z); s1.w = f2bf(b1.w);
      *(ushort4*)&kb[i] = s0;
      *(ushort4*)&kb[i + 4] = s1;
    }
    return;
  }
  const float* W = (z == 0) ? Wq : (z == 1) ? Wk : Wv;
  __shared__ float tile[32][33];
  int n0 = blockIdx.x * 32, k0 = blockIdx.y * 32;
  int tx = threadIdx.x;
  for (int j = threadIdx.y; j < 32; j += 8)
    tile[j][tx] = W[(size_t)(k0 + j) * DM + n0 + tx];
  __syncthreads();
  unsigned short* o = Wt + (size_t)z * DM * DM;
  for (int j = threadIdx.y; j < 32; j += 8)
    o[(size_t)(n0 + j) * DM + k0 + tx] = f2bf(tile[tx][j]);
}

// ---------------- projection GEMM + fused masks + V-transpose epilogue ----------------
// grid (64 row, 8 col, 3): id%8 = row%8 -> all col-blocks of a row-strip share an XCD
// kmask written as ADDITIVE mask (0 / -1e30); qmask multiplicative (1 / 0).
__global__ __launch_bounds__(256, 4) void gemm_proj(
    const unsigned short* __restrict__ qb, const unsigned short* __restrict__ kb,
    const unsigned short* __restrict__ Wt,
    const float* __restrict__ bq, const float* __restrict__ bk, const float* __restrict__ bv,
    unsigned short* __restrict__ Pq, unsigned short* __restrict__ Pk,
    unsigned short* __restrict__ Pvt,
    float* __restrict__ qmask, float* __restrict__ kmask) {
  const int z = blockIdx.z;
  const unsigned short* A = (z == 0) ? qb : kb;
  const unsigned short* Bt = Wt + (size_t)z * DM * DM;
  const float* bias = (z == 0) ? bq : (z == 1) ? bk : bv;

  __shared__ unsigned short smem[16384];
  unsigned short* As = smem;
  unsigned short* Bs = smem + 8192;

  const int tid = threadIdx.x;
  const int lane = tid & 63;
  const int wave = tid >> 6;
  const int l16 = lane & 15, quad = lane >> 4;
  const int wm = wave & 1, wn = wave >> 1;
  const int rowBase = blockIdx.x * 128;
  const int colBase = blockIdx.y * 128;

  floatx4 acc[4][4];
  const floatx4 zf = {0.f, 0.f, 0.f, 0.f};
#pragma unroll
  for (int i = 0; i < 4; i++)
#pragma unroll
    for (int j = 0; j < 4; j++) acc[i][j] = zf;

  const int srl = lane >> 3;
  const int sl7 = lane & 7;

  for (int kt = 0; kt < DM; kt += 64) {
#pragma unroll
    for (int cc = wave; cc < 16; cc += 4) {
      const int rl = cc * 8 + srl;
      const int ck = (sl7 ^ (rl & 7)) * 8;
      async_load16(A + (size_t)(rowBase + rl) * DM + kt + ck, &As[cc * 512]);
      async_load16(Bt + (size_t)(colBase + rl) * DM + kt + ck, &Bs[cc * 512]);
    }
    __syncthreads();

#pragma unroll
    for (int c = 0; c < 2; c++) {
      const int chnk = ((c << 2) + quad) ^ (l16 & 7);
      short8 af[4], bfr[4];
#pragma unroll
      for (int i = 0; i < 4; i++)
        af[i] = *(const short8*)&As[(wm * 64 + i * 16 + l16) * 64 + chnk * 8];
#pragma unroll
      for (int j = 0; j < 4; j++)
        bfr[j] = *(const short8*)&Bs[(wn * 64 + j * 16 + l16) * 64 + chnk * 8];
#pragma unroll
      for (int i = 0; i < 4; i++)
#pragma unroll
        for (int j = 0; j < 4; j++)
          acc[i][j] = __builtin_amdgcn_mfma_f32_16x16x32_bf16(af[i], bfr[j], acc[i][j], 0, 0, 0);
    }
    __syncthreads();
  }

#pragma unroll
  for (int j = 0; j < 4; j++) {
    const float bj = bias[colBase + wn * 64 + j * 16 + l16];
#pragma unroll
    for (int i = 0; i < 4; i++)
#pragma unroll
      for (int r = 0; r < 4; r++) acc[i][j][r] += bj;
  }

  if (z < 2) {
    float* mask = (z == 0) ? qmask : kmask;
    const int h = (colBase >> 6) + wn;
#pragma unroll
    for (int i = 0; i < 4; i++)
#pragma unroll
      for (int r = 0; r < 4; r++) {
        float rs = acc[i][0][r] + acc[i][1][r] + acc[i][2][r] + acc[i][3][r];
        rs += __shfl_xor(rs, 1);
        rs += __shfl_xor(rs, 2);
        rs += __shfl_xor(rs, 4);
        rs += __shfl_xor(rs, 8);
        if (l16 == 0) {
          const int row = rowBase + wm * 64 + i * 16 + quad * 4 + r;
          const float mv = (z == 0) ? ((rs != 0.f) ? 1.f : 0.f)
                                    : ((rs != 0.f) ? 0.f : -1e30f);
          mask[((size_t)((row >> 10) * NH + h)) * LSEQ + (row & 1023)] = mv;
        }
      }
    unsigned short* P = (z == 0) ? Pq : Pk;
#pragma unroll
    for (int j = 0; j < 4; j++) {
      const int col = colBase + wn * 64 + j * 16 + l16;
      const int hh = col >> 6, d = col & 63;
#pragma unroll
      for (int i = 0; i < 4; i++) {
        const int row0 = rowBase + wm * 64 + i * 16 + quad * 4;
#pragma unroll
        for (int r = 0; r < 4; r++) {
          const int rr = row0 + r;
          P[((size_t)((rr >> 10) * NH + hh) * LSEQ + (rr & 1023)) * DQ + d] = f2bf(acc[i][j][r]);
        }
      }
    }
  } else {
    const int b = rowBase >> 10;
    const int l0r = rowBase & 1023;
#pragma unroll
    for (int j = 0; j < 4; j++) {
      __syncthreads();
#pragma unroll
      for (int i = 0; i < 4; i++) {
        ushort4 v;
        v.x = f2bf(acc[i][j][0]); v.y = f2bf(acc[i][j][1]);
        v.z = f2bf(acc[i][j][2]); v.w = f2bf(acc[i][j][3]);
        *(ushort4*)&smem[(wn * 16 + l16) * 136 + wm * 64 + i * 16 + quad * 4] = v;
      }
      __syncthreads();
      const int c = tid >> 3, seg = tid & 7;
      const int col = colBase + (c >> 4) * 64 + j * 16 + (c & 15);
      const int hh = col >> 6, d = col & 63;
      int4 t0 = *(const int4*)&smem[c * 136 + seg * 16];
      int4 t1 = *(const int4*)&smem[c * 136 + seg * 16 + 8];
      const size_t g = ((size_t)((b * NH + hh) * DQ + d)) * LSEQ + l0r + seg * 16;
      *(int4*)&Pvt[g] = t0;
      *(int4*)&Pvt[g + 8] = t1;
    }
  }
}

// ---------------- flash attention v5: hoisted K-frags, additive kmask, dbuf ----------------
__global__ __launch_bounds__(256, 3) void attn_kernel(
    const unsigned short* __restrict__ Q, const unsigned short* __restrict__ K,
    const unsigned short* __restrict__ Vt,  // [b][h][d][l]
    const float* __restrict__ kmask, const float* __restrict__ qmask,
    const float* __restrict__ qin, float* __restrict__ out) {
  const int bh = blockIdx.x;          // id%8 = bh%8 -> all qblks of a bh share an XCD
  const int qblk = 7 - blockIdx.y;    // heavy q-blocks first
  const int b = bh >> 4, h = bh & 15;
  const size_t base = (size_t)bh * LSEQ * DQ;

  const int tid = threadIdx.x;
  const int lane = tid & 63;
  const int wave = tid >> 6;
  const int l16 = lane & 15, quad = lane >> 4;
  const int qw = qblk * 128 + wave * 32;

  __shared__ unsigned short Ks[2 * 4096];
  __shared__ unsigned short Vs[2 * 4096];
  __shared__ unsigned short Ps[4][2304];

  short8 qf[2][2];
#pragma unroll
  for (int sub = 0; sub < 2; sub++)
#pragma unroll
    for (int c = 0; c < 2; c++) {
      short8 t = *(const short8*)&Q[base + (size_t)(qw + sub * 16 + l16) * DQ + c * 32 + quad * 8];
#pragma unroll
      for (int e = 0; e < 8; e++) t[e] = (short)f2bf(bf2f((unsigned short)t[e]) * 0.125f);
      qf[sub][c] = t;
    }

  const floatx4 zf = {0.f, 0.f, 0.f, 0.f};
  floatx4 o[2][4];
#pragma unroll
  for (int sub = 0; sub < 2; sub++)
#pragma unroll
    for (int jj = 0; jj < 4; jj++) o[sub][jj] = zf;
  float l_p[2][4] = {{0.f, 0.f, 0.f, 0.f}, {0.f, 0.f, 0.f, 0.f}};

  const int swz = (quad ^ (l16 & 7)) * 8;
  const int swz2 = ((quad + 4) ^ (l16 & 7)) * 8;
  const int vswz = (quad ^ (l16 >> 1)) * 8;
  const int vswz2 = ((quad + 4) ^ (l16 >> 1)) * 8;

  const int srl = (lane >> 3);
  const int ktiles = (qblk + 1) * 2;
  const int tmax = 2 * qblk + (wave >> 1);

  {
#pragma unroll
    for (int cc = wave; cc < 8; cc += 4) {
      const int rl = cc * 8 + srl;
      const int ck = ((lane & 7) ^ (rl & 7)) * 8;
      async_load16(&K[base + (size_t)rl * DQ + ck], &Ks[cc * 512]);
      const int cv = ((lane & 7) ^ ((rl >> 1) & 7)) * 8;
      async_load16(&Vt[base + (size_t)rl * LSEQ + cv], &Vs[cc * 512]);
    }
  }
  __syncthreads();

  for (int t = 0; t < ktiles; t++) {
    const int cur = t & 1;
    const int kt = t * 64;
    const bool live = (t <= tmax);

    // additive kmask prefetch (0 or -1e30) before staging issues
    float km[4];
    if (live) {
#pragma unroll
      for (int ct = 0; ct < 4; ct++) km[ct] = kmask[(size_t)bh * LSEQ + kt + ct * 16 + l16];
    }

    if (t + 1 < ktiles) {
      const int nkt = kt + 64;
      const int nb = (cur ^ 1) * 4096;
#pragma unroll
      for (int cc = wave; cc < 8; cc += 4) {
        const int rl = cc * 8 + srl;
        const int ck = ((lane & 7) ^ (rl & 7)) * 8;
        async_load16(&K[base + (size_t)(nkt + rl) * DQ + ck], &Ks[nb + cc * 512]);
        const int cv = ((lane & 7) ^ ((rl >> 1) & 7)) * 8;
        async_load16(&Vt[base + (size_t)rl * LSEQ + nkt + cv], &Vs[nb + cc * 512]);
      }
    }

    if (live) {
      const unsigned short* Kb = &Ks[cur * 4096];
      const unsigned short* Vb = &Vs[cur * 4096];
      const bool diag = (t == tmax);

      // hoisted K fragments: 8 b128 reads, reused by both subs
      short8 kf[8];
#pragma unroll
      for (int ct = 0; ct < 4; ct++) {
        const int kr = (ct * 16 + l16) * 64;
        kf[2 * ct] = *(const short8*)&Kb[kr + swz];
        kf[2 * ct + 1] = *(const short8*)&Kb[kr + swz2];
      }
      // 16 S-MFMAs, 8 independent chains
      floatx4 s[2][4];
#pragma unroll
      for (int sub = 0; sub < 2; sub++)
#pragma unroll
        for (int ct = 0; ct < 4; ct++) {
          floatx4 sv = zf;
          sv = __builtin_amdgcn_mfma_f32_16x16x32_bf16(qf[sub][0], kf[2 * ct], sv, 0, 0, 0);
          sv = __builtin_amdgcn_mfma_f32_16x16x32_bf16(qf[sub][1], kf[2 * ct + 1], sv, 0, 0, 0);
          s[sub][ct] = sv;
        }

#pragma unroll
      for (int sub = 0; sub < 2; sub++) {
        const int row0 = qw + sub * 16 + quad * 4;
        unsigned short* pw = &Ps[wave][(sub * 16 + quad * 4) * 72];
        if (diag) {
#pragma unroll
          for (int ct = 0; ct < 4; ct++) {
            const int col = kt + ct * 16 + l16;
#pragma unroll
            for (int r = 0; r < 4; r++) {
              float e = __expf(s[sub][ct][r] + km[ct]);
              e = (col <= row0 + r) ? e : 0.f;
              l_p[sub][r] += e;
              pw[r * 72 + ct * 16 + l16] = f2bf(e);
            }
          }
        } else {
#pragma unroll
          for (int ct = 0; ct < 4; ct++) {
#pragma unroll
            for (int r = 0; r < 4; r++) {
              float e = __expf(s[sub][ct][r] + km[ct]);
              l_p[sub][r] += e;
              pw[r * 72 + ct * 16 + l16] = f2bf(e);
            }
          }
        }
      }
      asm volatile("s_waitcnt lgkmcnt(0)" ::: "memory");

      short8 pf[2][2];
#pragma unroll
      for (int sub = 0; sub < 2; sub++) {
        pf[sub][0] = *(const short8*)&Ps[wave][(sub * 16 + l16) * 72 + quad * 8];
        pf[sub][1] = *(const short8*)&Ps[wave][(sub * 16 + l16) * 72 + 32 + quad * 8];
      }
#pragma unroll
      for (int jj = 0; jj < 4; jj++) {
        const int vr = (jj * 16 + l16) * 64;
        const short8 vf0 = *(const short8*)&Vb[vr + vswz];
        const short8 vf1 = *(const short8*)&Vb[vr + vswz2];
#pragma unroll
        for (int sub = 0; sub < 2; sub++) {
          o[sub][jj] = __builtin_amdgcn_mfma_f32_16x16x32_bf16(pf[sub][0], vf0, o[sub][jj], 0, 0, 0);
          o[sub][jj] = __builtin_amdgcn_mfma_f32_16x16x32_bf16(pf[sub][1], vf1, o[sub][jj], 0, 0, 0);
        }
      }
    }
    __syncthreads();
  }

  const int hd = h * DQ;
#pragma unroll
  for (int sub = 0; sub < 2; sub++)
#pragma unroll
    for (int r = 0; r < 4; r++) {
      float lv = l_p[sub][r];
      lv += __shfl_xor(lv, 1);
      lv += __shfl_xor(lv, 2);
      lv += __shfl_xor(lv, 4);
      lv += __shfl_xor(lv, 8);
      const int row = qw + sub * 16 + quad * 4 + r;
      const float inv = qmask[(size_t)bh * LSEQ + row] / lv;
#pragma unroll
      for (int jj = 0; jj < 4; jj++) {
        const size_t oi = ((size_t)(b * LSEQ + row)) * DM + hd + jj * 16 + l16;
        out[oi] = o[sub][jj][r] * inv + qin[oi];
      }
    }
}

// ---------------- launch ----------------
extern "C" void kernel_launch(void* const* d_in, const int* in_sizes, int n_in,
                              void* d_out, int out_size, void* d_ws, size_t ws_size,
                              hipStream_t stream) {
  const float* q = (const float*)d_in[0];
  const float* k = (const float*)d_in[1];
  const float* Wq = (const float*)d_in[3];
  const float* bq = (const float*)d_in[4];
  const float* Wk = (const float*)d_in[5];
  const float* bk = (const float*)d_in[6];
  const float* Wv = (const float*)d_in[7];
  const float* bv = (const float*)d_in[8];
  float* out = (float*)d_out;

  char* w = (char*)d_ws;
  unsigned short* qb = (unsigned short*)(w + 0);
  unsigned short* kb = (unsigned short*)(w + 16777216);
  unsigned short* Wt = (unsigned short*)(w + 33554432);
  unsigned short* Pq = (unsigned short*)(w + 39845888);
  unsigned short* Pk = (unsigned short*)(w + 56623104);
  unsigned short* Pvt = (unsigned short*)(w + 73400320);
  float* qmask = (float*)(w + 90177536);
  float* kmask = (float*)(w + 90701824);

  prep_kernel<<<dim3(32, 32, 4), dim3(32, 8), 0, stream>>>(q, k, Wq, Wk, Wv, qb, kb, Wt);
  gemm_proj<<<dim3(64, 8, 3), 256, 0, stream>>>(qb, kb, Wt, bq, bk, bv,
                                                Pq, Pk, Pvt, qmask, kmask);
  attn_kernel<<<dim3(128, 8), 256, 0, stream>>>(Pq, Pk, Pvt, kmask, qmask, q, out);
}